// Round 9
// baseline (117.197 us; speedup 1.0000x reference)
//
#include <hip/hip_runtime.h>
#include <stdint.h>

// RBF kernel regression: out = exp(-gamma*d2(Xq,Xt)) @ alpha
// out[m] = ea[m] * sum_n w[n] * 2^( S[m][n] ),  S = (2*gamma*log2e*Xq).Xt^T
//
// R9: kill the 4x-redundant B loads (R8 analysis: L1 port 1024 cyc/ct/CU vs
// MFMA 1242 — two saturated pipes, 40% util). B tile now staged once per
// block: regular global loads -> regs -> ds_write, double-buffered, and the
// per-ct barrier is a fence-light "s_waitcnt lgkmcnt(0); s_barrier" (inline
// asm) so register-destined global prefetch loads are NOT drained (the m97
// vmcnt(0)-at-__syncthreads stall). NOT global_load_lds (R1-R5: that path's
// traffic bypassed L2, dur pinned at bytes/3TB/s).
// New per-ct CU budget: MFMA 1242 cyc (dominant), LDS ~960, L1 ~160.

#define MM 8192
#define NN 8192
#define DD 256
#define GAMMA (1.0f/256.0f)
#define LOG2E 1.44269504088896340736f
#define SCALE_A (2.0f*GAMMA*LOG2E)
#define NEG_G_LOG2E (-GAMMA*LOG2E)

#define NSPLIT 16
#define NPB (NN/NSPLIT)     // 512 cols per block
#define NT_PER (NPB/16)     // 32 column-tiles of 16

typedef __bf16 bf16x8 __attribute__((ext_vector_type(8)));
typedef float  f32x4  __attribute__((ext_vector_type(4)));

// ws: [0,4MB) A frag-linear; [4MB,8MB) B frag-linear; [8MB,+32K) w;
//     [+32K] ea; [+64K] part[16][8192] f32
#define A_OFF  ((size_t)0)
#define B_OFF  ((size_t)4 << 20)
#define W_OFF  ((size_t)8 << 20)
#define EA_OFF (((size_t)8 << 20) + 32768)
#define PART_OFF (((size_t)8 << 20) + 65536)

// lgkm-only barrier: waits DS ops (visibility of ds_write across waves)
// WITHOUT draining vmcnt — register-destined global prefetches stay in flight.
#define BAR_LGKM() asm volatile("s_waitcnt lgkmcnt(0)\ns_barrier" ::: "memory")

__device__ __forceinline__ unsigned short f2bf(float f) {  // RNE f32->bf16
  union { float f; uint32_t u; } x; x.f = f;
  uint32_t u = x.u;
  u += 0x7FFFu + ((u >> 16) & 1u);
  return (unsigned short)(u >> 16);
}
__device__ __forceinline__ uint32_t pack2(float a, float b) {
  return (uint32_t)f2bf(a) | ((uint32_t)f2bf(b) << 16);
}

// One wave per 16-row/col tile. Fragment-linear pack: tile t, round r, lane l
// writes dst + t*8192 + r*1024 + l*16 holding k-granule g=r*4+(l>>4) of
// row/col n=t*16+(l&15) — exactly the mfma_16x16x32 A/B operand layout.
__global__ __launch_bounds__(256) void prep_kernel(
    const float* __restrict__ Xq, const float* __restrict__ Xt,
    const float* __restrict__ alpha,
    char* __restrict__ Amat, char* __restrict__ Bmat,
    float* __restrict__ w, float* __restrict__ ea)
{
  const int lane = threadIdx.x & 63;
  const int gw = blockIdx.x * 4 + (threadIdx.x >> 6);  // 0..1023
  const bool isA = gw < 512;
  const int t = isA ? gw : gw - 512;
  const float* __restrict__ src = isA ? Xq : Xt;
  char* __restrict__ dst = isA ? Amat : Bmat;
  const float sc = isA ? SCALE_A : 1.0f;
  const int n = t * 16 + (lane & 15);
  float ss = 0.f;
#pragma unroll
  for (int r = 0; r < 8; ++r) {
    const int gg = r * 4 + (lane >> 4);
    const float* p = src + (size_t)n * DD + gg * 8;
    const float4 f0 = *(const float4*)p;
    const float4 f1 = *(const float4*)(p + 4);
    ss += f0.x*f0.x + f0.y*f0.y + f0.z*f0.z + f0.w*f0.w
        + f1.x*f1.x + f1.y*f1.y + f1.z*f1.z + f1.w*f1.w;
    uint4 pk;
    pk.x = pack2(f0.x * sc, f0.y * sc); pk.y = pack2(f0.z * sc, f0.w * sc);
    pk.z = pack2(f1.x * sc, f1.y * sc); pk.w = pack2(f1.z * sc, f1.w * sc);
    *(uint4*)(dst + (size_t)t * 8192 + r * 1024 + lane * 16) = pk;
  }
  ss += __shfl_xor(ss, 16, 64);   // reduce the 4 lanes holding col n
  ss += __shfl_xor(ss, 32, 64);
  if (lane < 16) {
    if (isA) ea[n] = __builtin_amdgcn_exp2f(NEG_G_LOG2E * ss);
    else     w[n]  = alpha[n] * __builtin_amdgcn_exp2f(NEG_G_LOG2E * ss);
  }
}

__global__ __launch_bounds__(256, 2) void rbf_main(
    const char* __restrict__ Amat, const char* __restrict__ Bmat,
    const float* __restrict__ w, const float* __restrict__ ea,
    float* __restrict__ part)
{
  __shared__ char  ldsB[2 * 8192];   // double-buffered B tile (8 KB each)
  __shared__ float lds_w[NPB];       // block's w slice (2 KB)
  const int tid  = threadIdx.x;
  const int wave = tid >> 6, lane = tid & 63;
  const int quad = lane >> 4, l16 = lane & 15;

  // 512 blocks = 32 my x 16 nx; XCD b&7 gets 8 my x 8 nx
  const int b    = blockIdx.x;
  const int xcd  = b & 7, slot = b >> 3;             // slot 0..63
  const int my   = (xcd & 3) * 8 + (slot & 7);       // 0..31 (256 rows each)
  const int nx   = (xcd >> 2) * 8 + (slot >> 3);     // 0..15
  const int mt0    = my * 16 + wave * 4;             // 4 mtiles = 64 rows/wave
  const int nt0    = nx * NT_PER;
  const int nbase0 = nx * NPB;

  // --- staging helpers: wave w owns granule-rows {2w, 2w+1} of each B tile
  uint4 greg[2];
  auto loadG = [&](int ct) {
    const char* g = Bmat + (size_t)(nt0 + ct) * 8192 + wave * 2048 + lane * 16;
    greg[0] = *(const uint4*)g;
    greg[1] = *(const uint4*)(g + 1024);
  };
  auto stageW = [&](int buf) {
    char* l = ldsB + buf * 8192 + wave * 2048 + lane * 16;
    *(uint4*)l = greg[0];
    *(uint4*)(l + 1024) = greg[1];
  };

  loadG(0);  // in flight during afrag + w staging below

  // w slice -> LDS (visibility via first BAR_LGKM)
  {
    const float2 wv2 = *(const float2*)(w + nbase0 + tid * 2);
    lds_w[tid * 2]     = wv2.x;
    lds_w[tid * 2 + 1] = wv2.y;
  }

  // A fragments register-resident for full K=256: 4 mtiles x 8 kc = 128 VGPR
  bf16x8 afrag[4][8];
#pragma unroll
  for (int rt = 0; rt < 4; ++rt)
#pragma unroll
    for (int kc = 0; kc < 8; ++kc) {
      union { uint4 u; bf16x8 v; } cv;
      cv.u = *(const uint4*)(Amat + (size_t)(mt0 + rt) * 8192 + kc * 1024 + lane * 16);
      afrag[rt][kc] = cv.v;
    }

  stageW(0);
  loadG(1);
  BAR_LGKM();   // buf0 + lds_w visible; greg(1) still in flight

  float outacc[4][4] = {{0,0,0,0},{0,0,0,0},{0,0,0,0},{0,0,0,0}};
  const f32x4 fzero = {0.f, 0.f, 0.f, 0.f};

  for (int ct = 0; ct < NT_PER; ++ct) {
    const int buf = ct & 1;
    if (ct + 1 < NT_PER) stageW(buf ^ 1);   // ds_write tile ct+1 (waits greg vmcnt only)
    if (ct + 2 < NT_PER) loadG(ct + 2);     // prefetch 2 ahead (regs)

    const float wv = lds_w[ct * 16 + l16];
    f32x4 acc[4] = {fzero, fzero, fzero, fzero};   // 4 independent 8-deep chains
#pragma unroll
    for (int kc = 0; kc < 8; ++kc) {
      union { uint4 u; bf16x8 v; } cv;
      cv.u = *(const uint4*)(ldsB + buf * 8192 + kc * 1024 + lane * 16);
#pragma unroll
      for (int rt = 0; rt < 4; ++rt)
        acc[rt] = __builtin_amdgcn_mfma_f32_16x16x32_bf16(afrag[rt][kc], cv.v, acc[rt], 0, 0, 0);
    }
#pragma unroll
    for (int rt = 0; rt < 4; ++rt) {               // C/D: row=quad*4+reg, col=l16
      outacc[rt][0] += wv * __builtin_amdgcn_exp2f(acc[rt][0]);
      outacc[rt][1] += wv * __builtin_amdgcn_exp2f(acc[rt][1]);
      outacc[rt][2] += wv * __builtin_amdgcn_exp2f(acc[rt][2]);
      outacc[rt][3] += wv * __builtin_amdgcn_exp2f(acc[rt][3]);
    }
    BAR_LGKM();   // my ds_reads of buf done (consumed above); next tile visible
  }

  // reduce over the 16 columns (l16), write exclusive per-block partials
#pragma unroll
  for (int rt = 0; rt < 4; ++rt)
#pragma unroll
    for (int i = 0; i < 4; ++i) {
      float v = outacc[rt][i];
      v += __shfl_xor(v, 1, 64);
      v += __shfl_xor(v, 2, 64);
      v += __shfl_xor(v, 4, 64);
      v += __shfl_xor(v, 8, 64);
      if (l16 == 0) {
        const int row = my * 256 + wave * 64 + rt * 16 + quad * 4 + i;
        part[(size_t)nx * MM + row] = ea[row] * v;
      }
    }
}

__global__ __launch_bounds__(256) void reduce_kernel(
    const float* __restrict__ part, float* __restrict__ out)
{
  const int row = blockIdx.x * 256 + threadIdx.x;
  float s = 0.f;
#pragma unroll
  for (int i = 0; i < NSPLIT; ++i) s += part[(size_t)i * MM + row];
  out[row] = s;
}

extern "C" void kernel_launch(void* const* d_in, const int* in_sizes, int n_in,
                              void* d_out, int out_size, void* d_ws, size_t ws_size,
                              hipStream_t stream) {
  const float* Xq    = (const float*)d_in[0];
  const float* Xt    = (const float*)d_in[1];
  const float* alpha = (const float*)d_in[2];
  float* out = (float*)d_out;
  char*  ws  = (char*)d_ws;

  char*  Amat = ws + A_OFF;
  char*  Bmat = ws + B_OFF;
  float* w    = (float*)(ws + W_OFF);
  float* ea   = (float*)(ws + EA_OFF);
  float* part = (float*)(ws + PART_OFF);

  hipLaunchKernelGGL(prep_kernel, dim3(256), dim3(256), 0, stream,
                     Xq, Xt, alpha, Amat, Bmat, w, ea);
  hipLaunchKernelGGL(rbf_main, dim3(512), dim3(256), 0, stream,
                     Amat, Bmat, w, ea, part);
  hipLaunchKernelGGL(reduce_kernel, dim3(MM / 256), dim3(256), 0, stream,
                     part, out);
}

// Round 10
// 100.194 us; speedup vs baseline: 1.1697x; 1.1697x over previous
//
#include <hip/hip_runtime.h>
#include <stdint.h>

// RBF kernel regression: out = exp(-gamma*d2(Xq,Xt)) @ alpha
// out[m] = ea[m] * sum_n w[n] * 2^( S[m][n] ),  S = (2*gamma*log2e*Xq).Xt^T
//
// R10: R8 structure (LDS-free frag-linear GEMM, 64 rows/wave, register
// ping-pong B prefetch, w in LDS) + tile-level software pipeline: the exp
// epilogue of tile ct is deferred one tile (two acc sets, parity-rotated),
// so epi(ct) has no dependence on mfma(ct+1)'s stream and the scheduler can
// hide the ~150-cyc serial tail (last MFMA -> 16 v_exp -> 16 fmac) under the
// matrix pipe. R9 lesson: LDS-sharing B + per-ct barrier regressed (barrier
// bubbles at 2 waves/SIMD); reverted. R1-R5 lesson: global_load_lds traffic
// bypassed L2 (dur pinned at bytes/3TB/s); keep regular loads.

#define MM 8192
#define NN 8192
#define DD 256
#define GAMMA (1.0f/256.0f)
#define LOG2E 1.44269504088896340736f
#define SCALE_A (2.0f*GAMMA*LOG2E)
#define NEG_G_LOG2E (-GAMMA*LOG2E)

#define NSPLIT 16
#define NPB (NN/NSPLIT)     // 512 cols per block
#define NT_PER (NPB/16)     // 32 column-tiles of 16

typedef __bf16 bf16x8 __attribute__((ext_vector_type(8)));
typedef float  f32x4  __attribute__((ext_vector_type(4)));

// ws: [0,4MB) A frag-linear; [4MB,8MB) B frag-linear; [8MB,+32K) w;
//     [+32K] ea; [+64K] part[16][8192] f32
#define A_OFF  ((size_t)0)
#define B_OFF  ((size_t)4 << 20)
#define W_OFF  ((size_t)8 << 20)
#define EA_OFF (((size_t)8 << 20) + 32768)
#define PART_OFF (((size_t)8 << 20) + 65536)

__device__ __forceinline__ unsigned short f2bf(float f) {  // RNE f32->bf16
  union { float f; uint32_t u; } x; x.f = f;
  uint32_t u = x.u;
  u += 0x7FFFu + ((u >> 16) & 1u);
  return (unsigned short)(u >> 16);
}
__device__ __forceinline__ uint32_t pack2(float a, float b) {
  return (uint32_t)f2bf(a) | ((uint32_t)f2bf(b) << 16);
}

// One wave per 16-row/col tile. Fragment-linear pack: tile t, round r, lane l
// writes dst + t*8192 + r*1024 + l*16 holding k-granule g=r*4+(l>>4) of
// row/col n=t*16+(l&15) — exactly the mfma_16x16x32 A/B operand layout.
__global__ __launch_bounds__(256) void prep_kernel(
    const float* __restrict__ Xq, const float* __restrict__ Xt,
    const float* __restrict__ alpha,
    char* __restrict__ Amat, char* __restrict__ Bmat,
    float* __restrict__ w, float* __restrict__ ea)
{
  const int lane = threadIdx.x & 63;
  const int gw = blockIdx.x * 4 + (threadIdx.x >> 6);  // 0..1023
  const bool isA = gw < 512;
  const int t = isA ? gw : gw - 512;
  const float* __restrict__ src = isA ? Xq : Xt;
  char* __restrict__ dst = isA ? Amat : Bmat;
  const float sc = isA ? SCALE_A : 1.0f;
  const int n = t * 16 + (lane & 15);
  float ss = 0.f;
#pragma unroll
  for (int r = 0; r < 8; ++r) {
    const int gg = r * 4 + (lane >> 4);
    const float* p = src + (size_t)n * DD + gg * 8;
    const float4 f0 = *(const float4*)p;
    const float4 f1 = *(const float4*)(p + 4);
    ss += f0.x*f0.x + f0.y*f0.y + f0.z*f0.z + f0.w*f0.w
        + f1.x*f1.x + f1.y*f1.y + f1.z*f1.z + f1.w*f1.w;
    uint4 pk;
    pk.x = pack2(f0.x * sc, f0.y * sc); pk.y = pack2(f0.z * sc, f0.w * sc);
    pk.z = pack2(f1.x * sc, f1.y * sc); pk.w = pack2(f1.z * sc, f1.w * sc);
    *(uint4*)(dst + (size_t)t * 8192 + r * 1024 + lane * 16) = pk;
  }
  ss += __shfl_xor(ss, 16, 64);   // reduce the 4 lanes holding col n
  ss += __shfl_xor(ss, 32, 64);
  if (lane < 16) {
    if (isA) ea[n] = __builtin_amdgcn_exp2f(NEG_G_LOG2E * ss);
    else     w[n]  = alpha[n] * __builtin_amdgcn_exp2f(NEG_G_LOG2E * ss);
  }
}

__global__ __launch_bounds__(256, 2) void rbf_main(
    const char* __restrict__ Amat, const char* __restrict__ Bmat,
    const float* __restrict__ w, const float* __restrict__ ea,
    float* __restrict__ part)
{
  __shared__ float lds_w[NPB];   // 2 KB: the block's w slice (lgkm-only reads)
  const int tid  = threadIdx.x;
  const int wave = tid >> 6, lane = tid & 63;
  const int quad = lane >> 4, l16 = lane & 15;

  // 512 blocks = 32 my x 16 nx; XCD b&7 gets 8 my x 8 nx
  const int b    = blockIdx.x;
  const int xcd  = b & 7, slot = b >> 3;             // slot 0..63
  const int my   = (xcd & 3) * 8 + (slot & 7);       // 0..31 (256 rows each)
  const int nx   = (xcd >> 2) * 8 + (slot >> 3);     // 0..15
  const int mt0    = my * 16 + wave * 4;             // 4 mtiles = 64 rows/wave
  const int nt0    = nx * NT_PER;
  const int nbase0 = nx * NPB;

  // stage w slice to LDS (single barrier in the whole kernel)
  {
    const float2 wv2 = *(const float2*)(w + nbase0 + tid * 2);
    lds_w[tid * 2]     = wv2.x;
    lds_w[tid * 2 + 1] = wv2.y;
  }

  // A fragments register-resident for full K=256: 4 mtiles x 8 kc = 128 VGPR
  bf16x8 afrag[4][8];
#pragma unroll
  for (int rt = 0; rt < 4; ++rt)
#pragma unroll
    for (int kc = 0; kc < 8; ++kc) {
      union { uint4 u; bf16x8 v; } cv;
      cv.u = *(const uint4*)(Amat + (size_t)(mt0 + rt) * 8192 + kc * 1024 + lane * 16);
      afrag[rt][kc] = cv.v;
    }

  __syncthreads();   // lds_w ready

  float outacc[4][4] = {{0,0,0,0},{0,0,0,0},{0,0,0,0},{0,0,0,0}};

  uint4 bufA[8], bufB[8];
  auto loadB = [&](uint4* dst, int ct) {
#pragma unroll
    for (int kc = 0; kc < 8; ++kc)
      dst[kc] = *(const uint4*)(Bmat + (size_t)(nt0 + ct) * 8192 + kc * 1024 + lane * 16);
  };

  const f32x4 fzero = {0.f, 0.f, 0.f, 0.f};
  f32x4 accA[4], accB[4];

  auto mfmaInto = [&](f32x4* acc, const uint4* buf) {
#pragma unroll
    for (int rt = 0; rt < 4; ++rt) acc[rt] = fzero;
#pragma unroll
    for (int kc = 0; kc < 8; ++kc) {
      union { uint4 u; bf16x8 v; } cv; cv.u = buf[kc];
#pragma unroll
      for (int rt = 0; rt < 4; ++rt)
        acc[rt] = __builtin_amdgcn_mfma_f32_16x16x32_bf16(afrag[rt][kc], cv.v, acc[rt], 0, 0, 0);
    }
  };
  auto epi = [&](const f32x4* acc, int ct) {
    const float wv = lds_w[ct * 16 + l16];   // ds_read: no vmcnt interaction
#pragma unroll
    for (int rt = 0; rt < 4; ++rt) {         // C/D: row=quad*4+reg, col=l16
      outacc[rt][0] += wv * __builtin_amdgcn_exp2f(acc[rt][0]);
      outacc[rt][1] += wv * __builtin_amdgcn_exp2f(acc[rt][1]);
      outacc[rt][2] += wv * __builtin_amdgcn_exp2f(acc[rt][2]);
      outacc[rt][3] += wv * __builtin_amdgcn_exp2f(acc[rt][3]);
    }
  };

  // software pipeline: epilogue of tile ct deferred under mfma of tile ct+1
  loadB(bufA, 0);
  loadB(bufB, 1);
  mfmaInto(accA, bufA);                    // tile 0
  for (int ct = 0; ct < NT_PER - 2; ct += 2) {
    loadB(bufA, ct + 2);                   // refill A-buf (tile ct just consumed)
    mfmaInto(accB, bufB);                  // tile ct+1
    epi(accA, ct);                         //   ...interleaves with the above
    loadB(bufB, ct + 3);
    mfmaInto(accA, bufA);                  // tile ct+2
    epi(accB, ct + 1);                     //   ...interleaves
  }
  mfmaInto(accB, bufB);                    // tile NT_PER-1
  epi(accA, NT_PER - 2);
  epi(accB, NT_PER - 1);

  // reduce over the 16 columns (l16), write exclusive per-block partials
#pragma unroll
  for (int rt = 0; rt < 4; ++rt)
#pragma unroll
    for (int i = 0; i < 4; ++i) {
      float v = outacc[rt][i];
      v += __shfl_xor(v, 1, 64);
      v += __shfl_xor(v, 2, 64);
      v += __shfl_xor(v, 4, 64);
      v += __shfl_xor(v, 8, 64);
      if (l16 == 0) {
        const int row = my * 256 + wave * 64 + rt * 16 + quad * 4 + i;
        part[(size_t)nx * MM + row] = ea[row] * v;
      }
    }
}

__global__ __launch_bounds__(256) void reduce_kernel(
    const float* __restrict__ part, float* __restrict__ out)
{
  const int row = blockIdx.x * 256 + threadIdx.x;
  float s = 0.f;
#pragma unroll
  for (int i = 0; i < NSPLIT; ++i) s += part[(size_t)i * MM + row];
  out[row] = s;
}

extern "C" void kernel_launch(void* const* d_in, const int* in_sizes, int n_in,
                              void* d_out, int out_size, void* d_ws, size_t ws_size,
                              hipStream_t stream) {
  const float* Xq    = (const float*)d_in[0];
  const float* Xt    = (const float*)d_in[1];
  const float* alpha = (const float*)d_in[2];
  float* out = (float*)d_out;
  char*  ws  = (char*)d_ws;

  char*  Amat = ws + A_OFF;
  char*  Bmat = ws + B_OFF;
  float* w    = (float*)(ws + W_OFF);
  float* ea   = (float*)(ws + EA_OFF);
  float* part = (float*)(ws + PART_OFF);

  hipLaunchKernelGGL(prep_kernel, dim3(256), dim3(256), 0, stream,
                     Xq, Xt, alpha, Amat, Bmat, w, ea);
  hipLaunchKernelGGL(rbf_main, dim3(512), dim3(256), 0, stream,
                     Amat, Bmat, w, ea, part);
  hipLaunchKernelGGL(reduce_kernel, dim3(MM / 256), dim3(256), 0, stream,
                     part, out);
}